// Round 6
// baseline (64.674 us; speedup 1.0000x reference)
//
#include <hip/hip_runtime.h>
#include <cstdint>
#include <cstddef>

// SequentiallyDependentGater on MI355X — R6: nt-stream + coalesced fwu flush.
//
//   K1 proj_map : wave = 16 rows = one 16-step sub-chunk. No cross-wave sync
//                 after W staging. x streamed with NON-TEMPORAL float4 loads
//                 (no L2 allocation -> stream doesn't fight the caches),
//                 depth-2 prefetch, butterfly reduce, W in 80 VGPRs.
//                 fw rows parked in a private LDS slice; after the wave's
//                 16-state sim, lanes 0-31 flush the whole 512 B fwu block
//                 with ONE coalesced store (no per-row partial-line stores).
//   K2 scan_emit: block = 256 rows. Wave 0 redundantly scans its batch's 512
//                 sub-chunk maps (lane owns 8: serial compose + Hillis-Steele
//                 + 8-step walk) -> starts in LDS; fully parallel emit.
//
// Decision rule everywhere: samp = (logit > th), th = log(u/(1-u)) — monotone-
// equivalent to u < sigmoid(logit) incl. ties. K1's sim is the single point
// where decisions are made; K2 recomputes logit from identical fwu bits with
// the identical pure-add/select expression (bit-exact, no FMA contraction).

namespace {

constexpr int kB = 8;
constexpr int kS = 8192;
constexpr int kD = 1024;
constexpr int kRows = kB * kS;          // 65536
constexpr int kT = 16;                  // sub-chunk steps (per-wave sim unit)
constexpr int kCPB = kS / kT;           // 512 sub-chunks per batch
constexpr int kChunks = kB * kCPB;      // 4096
constexpr unsigned long long kIdMap = 0xFEDCBA9876543210ull;

typedef float f32x4 __attribute__((ext_vector_type(4)));

// window bit i = window[i] (oldest first). logit = fw0 + sum(bit_i * fw[i+1]).
// fwu row layout: [fw0, fw1, fw2, fw3] [fw4, u, th, pad]
__device__ __forceinline__ float logit_from_state(unsigned int w,
                                                  const float4& A,
                                                  const float4& Bv) {
  const float s1 = (w & 1u) ? A.y : 0.0f;
  const float s2 = (w & 2u) ? A.z : 0.0f;
  const float s3 = (w & 4u) ? A.w : 0.0f;
  const float s4 = (w & 8u) ? Bv.x : 0.0f;
  return A.x + (((s1 + s2) + s3) + s4);
}

// 16-entry 4-bit maps packed in u64; result[s] = b[a[s]] ("a then b").
__device__ __forceinline__ unsigned long long compose(unsigned long long a,
                                                      unsigned long long b) {
  unsigned long long r = 0;
#pragma unroll
  for (int s = 0; s < 16; ++s) {
    const unsigned int e = (unsigned int)(a >> (4 * s)) & 15u;
    r |= ((b >> (4 * e)) & 15ull) << (4 * s);
  }
  return r;
}

}  // namespace

// ---------------------------------------------------------------- K1
__global__ __launch_bounds__(256, 3) void proj_map_kernel(
    const float* __restrict__ x, const float* __restrict__ W,
    const float* __restrict__ noise, float* __restrict__ fwu,
    unsigned int* __restrict__ trajbuf, unsigned long long* __restrict__ maps) {
  __shared__ float Wl[kD * 5];       // 20 KB
  __shared__ float fl[4][kT * 8];    // 2 KB, PER-WAVE private slices
  const int tid = threadIdx.x;
  const int lane = tid & 63;
  const int wv = tid >> 6;                   // 0..3
  const int wid = blockIdx.x * 4 + wv;       // 0..4095 == sub-chunk id
  const int r0 = wid * kT;                   // wave's first row

  // Noise for this wave's 16 rows: issue load before the W barrier.
  float nu = 0.5f, nth = 0.0f;
  if (lane < kT) nu = noise[r0 + lane];

  // Stage W coalesced into LDS, then into per-lane registers.
  const float4* W4 = reinterpret_cast<const float4*>(W);
  float4* Wl4 = reinterpret_cast<float4*>(Wl);
#pragma unroll
  for (int i = 0; i < 5; ++i) Wl4[tid + 256 * i] = W4[tid + 256 * i];

  if (lane < kT) nth = logf(nu / (1.0f - nu));  // u==0 -> -inf -> samp 1
  __syncthreads();   // the ONLY cross-wave sync

  float wr[4][4][5];
#pragma unroll
  for (int j = 0; j < 4; ++j)
#pragma unroll
    for (int k = 0; k < 4; ++k) {
      const int d = j * 256 + lane * 4 + k;
#pragma unroll
      for (int f = 0; f < 5; ++f) wr[j][k][f] = Wl[d * 5 + f];
    }

  // Non-temporal x row prefetch: no L2 allocation for the 256 MB stream.
  auto prefetch_row = [&](float4(&v)[4], int t) {
    if (t < kT) {
      const f32x4* xp =
          reinterpret_cast<const f32x4*>(x + (size_t)(r0 + t) * kD);
#pragma unroll
      for (int j = 0; j < 4; ++j) {
        const f32x4 q = __builtin_nontemporal_load(xp + j * 64 + lane);
        v[j] = make_float4(q.x, q.y, q.z, q.w);
      }
    }
  };

  auto do_row = [&](const float4(&v)[4], int t) {
    float acc[5] = {0.f, 0.f, 0.f, 0.f, 0.f};
#pragma unroll
    for (int j = 0; j < 4; ++j) {
      const float e[4] = {v[j].x, v[j].y, v[j].z, v[j].w};
#pragma unroll
      for (int k = 0; k < 4; ++k)
#pragma unroll
        for (int f = 0; f < 5; ++f) acc[f] += e[k] * wr[j][k][f];
    }
#pragma unroll
    for (int off = 32; off >= 1; off >>= 1)
#pragma unroll
      for (int f = 0; f < 5; ++f) acc[f] += __shfl_xor(acc[f], off);

    const float u = __shfl(nu, t);
    const float th = __shfl(nth, t);
    if (lane == 0) {
      float4* ol = reinterpret_cast<float4*>(&fl[wv][t * 8]);
      ol[0] = make_float4(acc[0], acc[1], acc[2], acc[3]);
      ol[1] = make_float4(acc[4], u, th, 0.0f);
    }
  };

  // Depth-2 software pipeline over the wave's 16 rows.
  float4 va[4], vb[4];
  prefetch_row(va, 0);
  prefetch_row(vb, 1);
#pragma unroll 1
  for (int tp = 0; tp < 8; ++tp) {
    do_row(va, 2 * tp);
    prefetch_row(va, 2 * tp + 2);
    do_row(vb, 2 * tp + 1);
    prefetch_row(vb, 2 * tp + 3);
  }

  // 16-state / 16-step speculative sim from the wave's private LDS slice.
  // Same-wave LDS write->read: in-order, no barrier needed.
  {
    unsigned int cur = (unsigned int)(lane & 15);
    unsigned int traj = 0;
#pragma unroll
    for (int i = 0; i < kT; ++i) {
      const float4* p = reinterpret_cast<const float4*>(&fl[wv][i * 8]);
      const float4 A = p[0];
      const float4 Bv = p[1];  // Bv.x=fw4, Bv.y=u, Bv.z=th
      const unsigned int d = (logit_from_state(cur, A, Bv) > Bv.z) ? 1u : 0u;
      traj |= d << i;
      cur = (cur >> 1) | (d << 3);
    }
    if (lane < 16) trajbuf[(size_t)wid * 16 + lane] = traj;
    // lanes >=16 mirror lane&15 -> low 16 bits of each plane = map bitplanes.
    const unsigned long long b0 = __ballot((int)(cur & 1u));
    const unsigned long long b1 = __ballot((int)(cur & 2u));
    const unsigned long long b2 = __ballot((int)(cur & 4u));
    const unsigned long long b3 = __ballot((int)(cur & 8u));
    if (lane == 0) {
      unsigned long long m = 0;
#pragma unroll
      for (int s = 0; s < 16; ++s) {
        const unsigned long long e =
            ((b0 >> s) & 1ull) | (((b1 >> s) & 1ull) << 1) |
            (((b2 >> s) & 1ull) << 2) | (((b3 >> s) & 1ull) << 3);
        m |= e << (4 * s);
      }
      maps[wid] = m;
    }
  }

  // Coalesced fwu flush: lanes 0-31 store the wave's 512 B block in one go.
  if (lane < 32) {
    const float4 v = reinterpret_cast<const float4*>(&fl[wv][0])[lane];
    reinterpret_cast<float4*>(fwu + (size_t)r0 * 8)[lane] = v;
  }
}

// ---------------------------------------------------------------- K2
// Block = 256 rows (16 sub-chunks), 32 blocks per batch. Wave 0 redundantly
// scans the batch's 512 maps; emit is fully parallel.
__global__ __launch_bounds__(256) void scan_emit_kernel(
    const float* __restrict__ fwu, const unsigned long long* __restrict__ maps,
    const unsigned int* __restrict__ trajbuf, float* __restrict__ out) {
  __shared__ unsigned char starts_lds[kCPB];   // 512 B
  const int tid = threadIdx.x;
  const int lane = tid & 63;
  const int wv = tid >> 6;
  const int bid = blockIdx.x;
  const int b = bid >> 5;                      // batch (32 blocks/batch)
  const int row = bid * 256 + tid;

  // Issue independent loads early (latency hides under the scan).
  const float4* p = reinterpret_cast<const float4*>(fwu + (size_t)row * 8);
  const float4 A = p[0];
  const float4 Bv = p[1];

  if (wv == 0) {
    unsigned long long m[8];
    const unsigned long long* mb = maps + b * kCPB + lane * 8;
#pragma unroll
    for (int i = 0; i < 8; ++i) m[i] = mb[i];
    unsigned long long c = m[0];
#pragma unroll
    for (int i = 1; i < 8; ++i) c = compose(c, m[i]);
    unsigned long long scan = c;
#pragma unroll
    for (int off = 1; off < 64; off <<= 1) {
      const unsigned long long prev = __shfl_up(scan, off);
      if (lane >= off) scan = compose(prev, scan);
    }
    unsigned long long pref = __shfl_up(scan, 1);
    if (lane == 0) pref = kIdMap;
    unsigned int s = (unsigned int)(pref & 15ull);  // state entering chunk 8L
#pragma unroll
    for (int i = 0; i < 8; ++i) {
      starts_lds[lane * 8 + i] = (unsigned char)s;
      s = (unsigned int)((m[i] >> (4 * s)) & 15ull);
    }
  }
  __syncthreads();

  const int scl = (row & (kS - 1)) >> 4;   // batch-local sub-chunk 0..511
  const int scg = row >> 4;                // global sub-chunk
  const unsigned int st = (unsigned int)starts_lds[scl];
  const unsigned int traj = trajbuf[(size_t)scg * 16 + st];
  const int i = row & 15;
  unsigned int w;
  if (i >= 4)
    w = (traj >> (i - 4)) & 15u;
  else
    w = ((st >> i) | (traj << (4 - i))) & 15u;

  const float logit = logit_from_state(w, A, Bv);  // identical recompute
  const float pr = 1.0f / (1.0f + expf(-logit));
  const float lp = fminf(logit, 0.0f) - log1pf(expf(-fabsf(logit)));
  out[row] = lp;                                      // gate_logits (= logp)
  out[kRows + row] = pr;                              // gate_probs
  out[2 * kRows + row] = (float)((traj >> i) & 1u);   // gate_samples
}

extern "C" void kernel_launch(void* const* d_in, const int* in_sizes, int n_in,
                              void* d_out, int out_size, void* d_ws,
                              size_t ws_size, hipStream_t stream) {
  const float* x = (const float*)d_in[0];
  const float* W = (const float*)d_in[1];
  const float* noise = (const float*)d_in[2];
  float* out = (float*)d_out;

  // ws layout: fwu (65536*8 f32 = 2 MB) | trajbuf (4096*16 u32 = 256 KB)
  //            | maps (4096 u64 = 32 KB)
  float* fwu = (float*)d_ws;
  unsigned int* trajbuf =
      (unsigned int*)((char*)d_ws + (size_t)kRows * 8 * sizeof(float));
  unsigned long long* maps =
      (unsigned long long*)((char*)trajbuf +
                            (size_t)kChunks * 16 * sizeof(unsigned int));

  proj_map_kernel<<<kChunks / 4, 256, 0, stream>>>(x, W, noise, fwu, trajbuf,
                                                   maps);
  scan_emit_kernel<<<kRows / 256, 256, 0, stream>>>(fwu, maps, trajbuf, out);
}

// Round 7
// 59.621 us; speedup vs baseline: 1.0847x; 1.0847x over previous
//
#include <hip/hip_runtime.h>
#include <cstdint>
#include <cstddef>

// SequentiallyDependentGater on MI355X — R7: R5 schedule + nt x-stream +
// coalesced fwu group flush (no per-row global stores).
//
//   K1 proj_map : wave = 32 rows = 2 independent 16-step sub-chunks.
//                 After the W-staging barrier there is NO cross-wave sync:
//                 each wave streams its rows (depth-2 float4 NT prefetch,
//                 butterfly reduce, W in 80 VGPRs), parks fw rows in a
//                 PRIVATE LDS slice, sims its own 16-state/16-step sub-chunk
//                 inline (traj u32 + end-state map u64 via ballot bitplanes),
//                 then flushes the 512 B fwu group with ONE coalesced store.
//   K2 scan_emit: block = 256 rows. Wave 0 redundantly scans its batch's 512
//                 sub-chunk maps (lane owns 8: serial compose + Hillis-Steele
//                 + 8-step walk) -> starts in LDS; fully parallel emit.
//
// Decision rule everywhere: samp = (logit > th), th = log(u/(1-u)) — monotone-
// equivalent to u < sigmoid(logit) incl. ties. K1's sim is the single point
// where decisions are made; K2 recomputes logit from identical fwu bits with
// the identical pure-add/select expression (bit-exact, no FMA contraction).

namespace {

constexpr int kB = 8;
constexpr int kS = 8192;
constexpr int kD = 1024;
constexpr int kRows = kB * kS;          // 65536
constexpr int kT = 16;                  // sub-chunk steps (per-wave sim unit)
constexpr int kCPB = kS / kT;           // 512 sub-chunks per batch
constexpr int kChunks = kB * kCPB;      // 4096
constexpr int kRPW = 32;                // rows per wave in K1 (2 sub-chunks)
constexpr unsigned long long kIdMap = 0xFEDCBA9876543210ull;

typedef float f32x4 __attribute__((ext_vector_type(4)));

// window bit i = window[i] (oldest first). logit = fw0 + sum(bit_i * fw[i+1]).
// fwu row layout: [fw0, fw1, fw2, fw3] [fw4, u, th, pad]
__device__ __forceinline__ float logit_from_state(unsigned int w,
                                                  const float4& A,
                                                  const float4& Bv) {
  const float s1 = (w & 1u) ? A.y : 0.0f;
  const float s2 = (w & 2u) ? A.z : 0.0f;
  const float s3 = (w & 4u) ? A.w : 0.0f;
  const float s4 = (w & 8u) ? Bv.x : 0.0f;
  return A.x + (((s1 + s2) + s3) + s4);
}

// 16-entry 4-bit maps packed in u64; result[s] = b[a[s]] ("a then b").
__device__ __forceinline__ unsigned long long compose(unsigned long long a,
                                                      unsigned long long b) {
  unsigned long long r = 0;
#pragma unroll
  for (int s = 0; s < 16; ++s) {
    const unsigned int e = (unsigned int)(a >> (4 * s)) & 15u;
    r |= ((b >> (4 * e)) & 15ull) << (4 * s);
  }
  return r;
}

}  // namespace

// ---------------------------------------------------------------- K1
__global__ __launch_bounds__(256, 2) void proj_map_kernel(
    const float* __restrict__ x, const float* __restrict__ W,
    const float* __restrict__ noise, float* __restrict__ fwu,
    unsigned int* __restrict__ trajbuf, unsigned long long* __restrict__ maps) {
  __shared__ float Wl[kD * 5];       // 20 KB
  __shared__ float fl[4][kT * 8];    // 2 KB, PER-WAVE private slices
  const int tid = threadIdx.x;
  const int lane = tid & 63;
  const int wv = tid >> 6;                   // 0..3
  const int wid = blockIdx.x * 4 + wv;       // 0..2047
  const int r0 = wid * kRPW;                 // wave's first row

  // Noise for this wave's 32 rows: issue load before the W barrier.
  float nu = 0.5f, nth = 0.0f;
  if (lane < kRPW) nu = noise[r0 + lane];

  // Stage W coalesced into LDS, then into per-lane registers.
  const float4* W4 = reinterpret_cast<const float4*>(W);
  float4* Wl4 = reinterpret_cast<float4*>(Wl);
#pragma unroll
  for (int i = 0; i < 5; ++i) Wl4[tid + 256 * i] = W4[tid + 256 * i];

  if (lane < kRPW) nth = logf(nu / (1.0f - nu));  // u==0 -> -inf -> samp 1
  __syncthreads();   // the ONLY cross-wave sync

  float wr[4][4][5];
#pragma unroll
  for (int j = 0; j < 4; ++j)
#pragma unroll
    for (int k = 0; k < 4; ++k) {
      const int d = j * 256 + lane * 4 + k;
#pragma unroll
      for (int f = 0; f < 5; ++f) wr[j][k][f] = Wl[d * 5 + f];
    }

  // Non-temporal x prefetch: the 256 MB stream should not allocate in cache.
  auto prefetch_row = [&](float4(&v)[4], int t) {
    if (t < kRPW) {
      const f32x4* xp =
          reinterpret_cast<const f32x4*>(x + (size_t)(r0 + t) * kD);
#pragma unroll
      for (int j = 0; j < 4; ++j) {
        const f32x4 q = __builtin_nontemporal_load(xp + j * 64 + lane);
        v[j] = make_float4(q.x, q.y, q.z, q.w);
      }
    }
  };

  auto do_row = [&](const float4(&v)[4], int t) {
    float acc[5] = {0.f, 0.f, 0.f, 0.f, 0.f};
#pragma unroll
    for (int j = 0; j < 4; ++j) {
      const float e[4] = {v[j].x, v[j].y, v[j].z, v[j].w};
#pragma unroll
      for (int k = 0; k < 4; ++k)
#pragma unroll
        for (int f = 0; f < 5; ++f) acc[f] += e[k] * wr[j][k][f];
    }
#pragma unroll
    for (int off = 32; off >= 1; off >>= 1)
#pragma unroll
      for (int f = 0; f < 5; ++f) acc[f] += __shfl_xor(acc[f], off);

    const float u = __shfl(nu, t);
    const float th = __shfl(nth, t);
    if (lane == 0) {
      float4* ol = reinterpret_cast<float4*>(&fl[wv][(t & 15) * 8]);
      ol[0] = make_float4(acc[0], acc[1], acc[2], acc[3]);
      ol[1] = make_float4(acc[4], u, th, 0.0f);
    }
  };

  // 16-state / 16-step speculative sim of sub-chunk c from the wave's private
  // LDS slice. Same-wave LDS write->read: in-order, no barrier needed.
  auto sim = [&](int c) {
    unsigned int cur = (unsigned int)(lane & 15);
    unsigned int traj = 0;
#pragma unroll
    for (int i = 0; i < kT; ++i) {
      const float4* p = reinterpret_cast<const float4*>(&fl[wv][i * 8]);
      const float4 A = p[0];
      const float4 Bv = p[1];  // Bv.x=fw4, Bv.y=u, Bv.z=th
      const unsigned int d = (logit_from_state(cur, A, Bv) > Bv.z) ? 1u : 0u;
      traj |= d << i;
      cur = (cur >> 1) | (d << 3);
    }
    if (lane < 16) trajbuf[(size_t)c * 16 + lane] = traj;
    // lanes >=16 mirror lane&15 -> low 16 bits of each plane = map bitplanes.
    const unsigned long long b0 = __ballot((int)(cur & 1u));
    const unsigned long long b1 = __ballot((int)(cur & 2u));
    const unsigned long long b2 = __ballot((int)(cur & 4u));
    const unsigned long long b3 = __ballot((int)(cur & 8u));
    if (lane == 0) {
      unsigned long long m = 0;
#pragma unroll
      for (int s = 0; s < 16; ++s) {
        const unsigned long long e =
            ((b0 >> s) & 1ull) | (((b1 >> s) & 1ull) << 1) |
            (((b2 >> s) & 1ull) << 2) | (((b3 >> s) & 1ull) << 3);
        m |= e << (4 * s);
      }
      maps[c] = m;
    }
  };

  // Coalesced fwu flush of one 16-row group (512 B, lanes 0-31, one store).
  auto flush = [&](int g) {
    if (lane < 32) {
      const float4 v = reinterpret_cast<const float4*>(&fl[wv][0])[lane];
      reinterpret_cast<float4*>(fwu + (size_t)(r0 + g * kT) * 8)[lane] = v;
    }
  };

  // Depth-2 software pipeline over the wave's 32 rows; sims+flushes run
  // inline after each 16-row group, overlapped with in-flight next loads.
  float4 va[4], vb[4];
  prefetch_row(va, 0);
  prefetch_row(vb, 1);
#pragma unroll 1
  for (int tp = 0; tp < 16; ++tp) {
    do_row(va, 2 * tp);
    prefetch_row(va, 2 * tp + 2);
    do_row(vb, 2 * tp + 1);
    prefetch_row(vb, 2 * tp + 3);
    if (tp == 7) {
      sim(wid * 2);
      flush(0);
    }
    if (tp == 15) {
      sim(wid * 2 + 1);
      flush(1);
    }
  }
}

// ---------------------------------------------------------------- K2
// Block = 256 rows (16 sub-chunks), 32 blocks per batch. Wave 0 redundantly
// scans the batch's 512 maps; emit is fully parallel.
__global__ __launch_bounds__(256) void scan_emit_kernel(
    const float* __restrict__ fwu, const unsigned long long* __restrict__ maps,
    const unsigned int* __restrict__ trajbuf, float* __restrict__ out) {
  __shared__ unsigned char starts_lds[kCPB];   // 512 B
  const int tid = threadIdx.x;
  const int lane = tid & 63;
  const int wv = tid >> 6;
  const int bid = blockIdx.x;
  const int b = bid >> 5;                      // batch (32 blocks/batch)
  const int row = bid * 256 + tid;

  // Issue independent loads early (latency hides under the scan).
  const float4* p = reinterpret_cast<const float4*>(fwu + (size_t)row * 8);
  const float4 A = p[0];
  const float4 Bv = p[1];

  if (wv == 0) {
    unsigned long long m[8];
    const unsigned long long* mb = maps + b * kCPB + lane * 8;
#pragma unroll
    for (int i = 0; i < 8; ++i) m[i] = mb[i];
    unsigned long long c = m[0];
#pragma unroll
    for (int i = 1; i < 8; ++i) c = compose(c, m[i]);
    unsigned long long scan = c;
#pragma unroll
    for (int off = 1; off < 64; off <<= 1) {
      const unsigned long long prev = __shfl_up(scan, off);
      if (lane >= off) scan = compose(prev, scan);
    }
    unsigned long long pref = __shfl_up(scan, 1);
    if (lane == 0) pref = kIdMap;
    unsigned int s = (unsigned int)(pref & 15ull);  // state entering chunk 8L
#pragma unroll
    for (int i = 0; i < 8; ++i) {
      starts_lds[lane * 8 + i] = (unsigned char)s;
      s = (unsigned int)((m[i] >> (4 * s)) & 15ull);
    }
  }
  __syncthreads();

  const int scl = (row & (kS - 1)) >> 4;   // batch-local sub-chunk 0..511
  const int scg = row >> 4;                // global sub-chunk
  const unsigned int st = (unsigned int)starts_lds[scl];
  const unsigned int traj = trajbuf[(size_t)scg * 16 + st];
  const int i = row & 15;
  unsigned int w;
  if (i >= 4)
    w = (traj >> (i - 4)) & 15u;
  else
    w = ((st >> i) | (traj << (4 - i))) & 15u;

  const float logit = logit_from_state(w, A, Bv);  // identical recompute
  const float pr = 1.0f / (1.0f + expf(-logit));
  const float lp = fminf(logit, 0.0f) - log1pf(expf(-fabsf(logit)));
  out[row] = lp;                                      // gate_logits (= logp)
  out[kRows + row] = pr;                              // gate_probs
  out[2 * kRows + row] = (float)((traj >> i) & 1u);   // gate_samples
}

extern "C" void kernel_launch(void* const* d_in, const int* in_sizes, int n_in,
                              void* d_out, int out_size, void* d_ws,
                              size_t ws_size, hipStream_t stream) {
  const float* x = (const float*)d_in[0];
  const float* W = (const float*)d_in[1];
  const float* noise = (const float*)d_in[2];
  float* out = (float*)d_out;

  // ws layout: fwu (65536*8 f32 = 2 MB) | trajbuf (4096*16 u32 = 256 KB)
  //            | maps (4096 u64 = 32 KB)
  float* fwu = (float*)d_ws;
  unsigned int* trajbuf =
      (unsigned int*)((char*)d_ws + (size_t)kRows * 8 * sizeof(float));
  unsigned long long* maps =
      (unsigned long long*)((char*)trajbuf +
                            (size_t)kChunks * 16 * sizeof(unsigned int));

  proj_map_kernel<<<512, 256, 0, stream>>>(x, W, noise, fwu, trajbuf, maps);
  scan_emit_kernel<<<kRows / 256, 256, 0, stream>>>(fwu, maps, trajbuf, out);
}

// Round 8
// 55.399 us; speedup vs baseline: 1.1674x; 1.0762x over previous
//
#include <hip/hip_runtime.h>
#include <cstdint>
#include <cstddef>

// SequentiallyDependentGater on MI355X — R8: R5 schedule, depth-4 prefetch.
// Single-variable change vs R5 (54.9 µs best): prefetch pipeline depth 2 -> 4
// (16 KB in flight per wave) to cover queue-inflated HBM latency.
// nt-loads reverted (R6/R7 showed they cost ~+5 µs).
//
//   K1 proj_map : wave = 32 rows = 2 independent 16-step sub-chunks.
//                 After the W-staging barrier there is NO cross-wave sync:
//                 each wave streams its rows (depth-4 float4 prefetch,
//                 butterfly reduce, W in 80 VGPRs), parks fw rows in a
//                 PRIVATE LDS slice, and sims its own 16-state/16-step
//                 sub-chunk inline (traj u32 + end-state map u64 via ballot
//                 bitplanes). Per-row lane-0 fwu stores (R5 style).
//   K2 scan_emit: block = 256 rows. Wave 0 redundantly scans its batch's 512
//                 sub-chunk maps (lane owns 8: serial compose + Hillis-Steele
//                 + 8-step walk) -> starts in LDS; fully parallel emit.
//
// Decision rule everywhere: samp = (logit > th), th = log(u/(1-u)) — monotone-
// equivalent to u < sigmoid(logit) incl. ties. K1's sim is the single point
// where decisions are made; K2 recomputes logit from identical fwu bits with
// the identical pure-add/select expression (bit-exact, no FMA contraction).

namespace {

constexpr int kB = 8;
constexpr int kS = 8192;
constexpr int kD = 1024;
constexpr int kRows = kB * kS;          // 65536
constexpr int kT = 16;                  // sub-chunk steps (per-wave sim unit)
constexpr int kCPB = kS / kT;           // 512 sub-chunks per batch
constexpr int kChunks = kB * kCPB;      // 4096
constexpr int kRPW = 32;                // rows per wave in K1 (2 sub-chunks)
constexpr unsigned long long kIdMap = 0xFEDCBA9876543210ull;

// window bit i = window[i] (oldest first). logit = fw0 + sum(bit_i * fw[i+1]).
// fwu row layout: [fw0, fw1, fw2, fw3] [fw4, u, th, pad]
__device__ __forceinline__ float logit_from_state(unsigned int w,
                                                  const float4& A,
                                                  const float4& Bv) {
  const float s1 = (w & 1u) ? A.y : 0.0f;
  const float s2 = (w & 2u) ? A.z : 0.0f;
  const float s3 = (w & 4u) ? A.w : 0.0f;
  const float s4 = (w & 8u) ? Bv.x : 0.0f;
  return A.x + (((s1 + s2) + s3) + s4);
}

// 16-entry 4-bit maps packed in u64; result[s] = b[a[s]] ("a then b").
__device__ __forceinline__ unsigned long long compose(unsigned long long a,
                                                      unsigned long long b) {
  unsigned long long r = 0;
#pragma unroll
  for (int s = 0; s < 16; ++s) {
    const unsigned int e = (unsigned int)(a >> (4 * s)) & 15u;
    r |= ((b >> (4 * e)) & 15ull) << (4 * s);
  }
  return r;
}

}  // namespace

// ---------------------------------------------------------------- K1
__global__ __launch_bounds__(256, 2) void proj_map_kernel(
    const float* __restrict__ x, const float* __restrict__ W,
    const float* __restrict__ noise, float* __restrict__ fwu,
    unsigned int* __restrict__ trajbuf, unsigned long long* __restrict__ maps) {
  __shared__ float Wl[kD * 5];       // 20 KB
  __shared__ float fl[4][kT * 8];    // 2 KB, PER-WAVE private slices
  const int tid = threadIdx.x;
  const int lane = tid & 63;
  const int wv = tid >> 6;                   // 0..3
  const int wid = blockIdx.x * 4 + wv;       // 0..2047
  const int r0 = wid * kRPW;                 // wave's first row

  // Noise for this wave's 32 rows: issue load before the W barrier.
  float nu = 0.5f, nth = 0.0f;
  if (lane < kRPW) nu = noise[r0 + lane];

  // Stage W coalesced into LDS, then into per-lane registers.
  const float4* W4 = reinterpret_cast<const float4*>(W);
  float4* Wl4 = reinterpret_cast<float4*>(Wl);
#pragma unroll
  for (int i = 0; i < 5; ++i) Wl4[tid + 256 * i] = W4[tid + 256 * i];

  if (lane < kRPW) nth = logf(nu / (1.0f - nu));  // u==0 -> -inf -> samp 1
  __syncthreads();   // the ONLY cross-wave sync

  float wr[4][4][5];
#pragma unroll
  for (int j = 0; j < 4; ++j)
#pragma unroll
    for (int k = 0; k < 4; ++k) {
      const int d = j * 256 + lane * 4 + k;
#pragma unroll
      for (int f = 0; f < 5; ++f) wr[j][k][f] = Wl[d * 5 + f];
    }

  auto prefetch_row = [&](float4(&v)[4], int t) {
    if (t < kRPW) {
      const float4* xp =
          reinterpret_cast<const float4*>(x + (size_t)(r0 + t) * kD);
#pragma unroll
      for (int j = 0; j < 4; ++j) v[j] = xp[j * 64 + lane];
    }
  };

  auto do_row = [&](const float4(&v)[4], int t) {
    float acc[5] = {0.f, 0.f, 0.f, 0.f, 0.f};
#pragma unroll
    for (int j = 0; j < 4; ++j) {
      const float e[4] = {v[j].x, v[j].y, v[j].z, v[j].w};
#pragma unroll
      for (int k = 0; k < 4; ++k)
#pragma unroll
        for (int f = 0; f < 5; ++f) acc[f] += e[k] * wr[j][k][f];
    }
#pragma unroll
    for (int off = 32; off >= 1; off >>= 1)
#pragma unroll
      for (int f = 0; f < 5; ++f) acc[f] += __shfl_xor(acc[f], off);

    const float u = __shfl(nu, t);
    const float th = __shfl(nth, t);
    if (lane == 0) {
      const float4 o0 = make_float4(acc[0], acc[1], acc[2], acc[3]);
      const float4 o1 = make_float4(acc[4], u, th, 0.0f);
      float4* og = reinterpret_cast<float4*>(fwu + (size_t)(r0 + t) * 8);
      og[0] = o0;
      og[1] = o1;
      float4* ol = reinterpret_cast<float4*>(&fl[wv][(t & 15) * 8]);
      ol[0] = o0;
      ol[1] = o1;
    }
  };

  // 16-state / 16-step speculative sim of sub-chunk c from the wave's private
  // LDS slice. Same-wave LDS write->read: in-order, no barrier needed.
  auto sim = [&](int c) {
    unsigned int cur = (unsigned int)(lane & 15);
    unsigned int traj = 0;
#pragma unroll
    for (int i = 0; i < kT; ++i) {
      const float4* p = reinterpret_cast<const float4*>(&fl[wv][i * 8]);
      const float4 A = p[0];
      const float4 Bv = p[1];  // Bv.x=fw4, Bv.y=u, Bv.z=th
      const unsigned int d = (logit_from_state(cur, A, Bv) > Bv.z) ? 1u : 0u;
      traj |= d << i;
      cur = (cur >> 1) | (d << 3);
    }
    if (lane < 16) trajbuf[(size_t)c * 16 + lane] = traj;
    // lanes >=16 mirror lane&15 -> low 16 bits of each plane = map bitplanes.
    const unsigned long long b0 = __ballot((int)(cur & 1u));
    const unsigned long long b1 = __ballot((int)(cur & 2u));
    const unsigned long long b2 = __ballot((int)(cur & 4u));
    const unsigned long long b3 = __ballot((int)(cur & 8u));
    if (lane == 0) {
      unsigned long long m = 0;
#pragma unroll
      for (int s = 0; s < 16; ++s) {
        const unsigned long long e =
            ((b0 >> s) & 1ull) | (((b1 >> s) & 1ull) << 1) |
            (((b2 >> s) & 1ull) << 2) | (((b3 >> s) & 1ull) << 3);
        m |= e << (4 * s);
      }
      maps[c] = m;
    }
  };

  // Depth-4 software pipeline over the wave's 32 rows (16 KB in flight).
  // Sims run inline after each 16-row group, overlapped with in-flight loads
  // for the next group's rows.
  float4 va[4], vb[4], vc[4], vd[4];
  prefetch_row(va, 0);
  prefetch_row(vb, 1);
  prefetch_row(vc, 2);
  prefetch_row(vd, 3);
#pragma unroll 1
  for (int g = 0; g < 8; ++g) {
    do_row(va, 4 * g);
    prefetch_row(va, 4 * g + 4);
    do_row(vb, 4 * g + 1);
    prefetch_row(vb, 4 * g + 5);
    do_row(vc, 4 * g + 2);
    prefetch_row(vc, 4 * g + 6);
    do_row(vd, 4 * g + 3);
    prefetch_row(vd, 4 * g + 7);
    if (g == 3) sim(wid * 2);
    if (g == 7) sim(wid * 2 + 1);
  }
}

// ---------------------------------------------------------------- K2
// Block = 256 rows (16 sub-chunks), 32 blocks per batch. Wave 0 redundantly
// scans the batch's 512 maps; emit is fully parallel.
__global__ __launch_bounds__(256) void scan_emit_kernel(
    const float* __restrict__ fwu, const unsigned long long* __restrict__ maps,
    const unsigned int* __restrict__ trajbuf, float* __restrict__ out) {
  __shared__ unsigned char starts_lds[kCPB];   // 512 B
  const int tid = threadIdx.x;
  const int lane = tid & 63;
  const int wv = tid >> 6;
  const int bid = blockIdx.x;
  const int b = bid >> 5;                      // batch (32 blocks/batch)
  const int row = bid * 256 + tid;

  // Issue independent loads early (latency hides under the scan).
  const float4* p = reinterpret_cast<const float4*>(fwu + (size_t)row * 8);
  const float4 A = p[0];
  const float4 Bv = p[1];

  if (wv == 0) {
    unsigned long long m[8];
    const unsigned long long* mb = maps + b * kCPB + lane * 8;
#pragma unroll
    for (int i = 0; i < 8; ++i) m[i] = mb[i];
    unsigned long long c = m[0];
#pragma unroll
    for (int i = 1; i < 8; ++i) c = compose(c, m[i]);
    unsigned long long scan = c;
#pragma unroll
    for (int off = 1; off < 64; off <<= 1) {
      const unsigned long long prev = __shfl_up(scan, off);
      if (lane >= off) scan = compose(prev, scan);
    }
    unsigned long long pref = __shfl_up(scan, 1);
    if (lane == 0) pref = kIdMap;
    unsigned int s = (unsigned int)(pref & 15ull);  // state entering chunk 8L
#pragma unroll
    for (int i = 0; i < 8; ++i) {
      starts_lds[lane * 8 + i] = (unsigned char)s;
      s = (unsigned int)((m[i] >> (4 * s)) & 15ull);
    }
  }
  __syncthreads();

  const int scl = (row & (kS - 1)) >> 4;   // batch-local sub-chunk 0..511
  const int scg = row >> 4;                // global sub-chunk
  const unsigned int st = (unsigned int)starts_lds[scl];
  const unsigned int traj = trajbuf[(size_t)scg * 16 + st];
  const int i = row & 15;
  unsigned int w;
  if (i >= 4)
    w = (traj >> (i - 4)) & 15u;
  else
    w = ((st >> i) | (traj << (4 - i))) & 15u;

  const float logit = logit_from_state(w, A, Bv);  // identical recompute
  const float pr = 1.0f / (1.0f + expf(-logit));
  const float lp = fminf(logit, 0.0f) - log1pf(expf(-fabsf(logit)));
  out[row] = lp;                                      // gate_logits (= logp)
  out[kRows + row] = pr;                              // gate_probs
  out[2 * kRows + row] = (float)((traj >> i) & 1u);   // gate_samples
}

extern "C" void kernel_launch(void* const* d_in, const int* in_sizes, int n_in,
                              void* d_out, int out_size, void* d_ws,
                              size_t ws_size, hipStream_t stream) {
  const float* x = (const float*)d_in[0];
  const float* W = (const float*)d_in[1];
  const float* noise = (const float*)d_in[2];
  float* out = (float*)d_out;

  // ws layout: fwu (65536*8 f32 = 2 MB) | trajbuf (4096*16 u32 = 256 KB)
  //            | maps (4096 u64 = 32 KB)
  float* fwu = (float*)d_ws;
  unsigned int* trajbuf =
      (unsigned int*)((char*)d_ws + (size_t)kRows * 8 * sizeof(float));
  unsigned long long* maps =
      (unsigned long long*)((char*)trajbuf +
                            (size_t)kChunks * 16 * sizeof(unsigned int));

  proj_map_kernel<<<512, 256, 0, stream>>>(x, W, noise, fwu, trajbuf, maps);
  scan_emit_kernel<<<kRows / 256, 256, 0, stream>>>(fwu, maps, trajbuf, out);
}